// Round 16
// baseline (183.284 us; speedup 1.0000x reference)
//
#include <hip/hip_runtime.h>

#define T_DIM 64
#define N_DIM 2000
#define C_DIM 64
#define E_DIM 32000
#define ROWS (T_DIM * N_DIM)   // 128000
#define BN_EPS 1e-5f
#define TCHUNK 4
#define GEMAX 1024             // LDS edge buffer (block of 8 n's; E[sum deg+1]~136)

typedef short s8v __attribute__((ext_vector_type(8)));
typedef float f4v __attribute__((ext_vector_type(4)));

__device__ __forceinline__ ushort f2b(float f) {
    unsigned u = __float_as_uint(f);
    unsigned r = u + 0x7FFF + ((u >> 16) & 1);
    return (ushort)(r >> 16);
}
__device__ __forceinline__ float b2f(ushort h) {
    return __uint_as_float(((unsigned)h) << 16);
}
__device__ __forceinline__ s8v pack8(float4 a, float4 b) {
    s8v r;
    r[0] = (short)f2b(a.x); r[1] = (short)f2b(a.y);
    r[2] = (short)f2b(a.z); r[3] = (short)f2b(a.w);
    r[4] = (short)f2b(b.x); r[5] = (short)f2b(b.y);
    r[6] = (short)f2b(b.z); r[7] = (short)f2b(b.w);
    return r;
}

// ---------------- prep: deg (int4-vectorized, LDS atomics) + scan + dinv + self-edge + cursor ----------------
__global__ void k_degscan(const int* __restrict__ ei, int* __restrict__ offs,
                          float* __restrict__ dinv, int* __restrict__ cursor,
                          int2* __restrict__ edat) {
    __shared__ int a[2048], b[2048];
    int tid = threadIdx.x;
    for (int i = tid; i < 2048; i += 1024) a[i] = 0;
    __syncthreads();
    // vectorized count: 8000 int4 loads instead of 32000 scalar
    for (int e4 = tid; e4 < E_DIM / 4; e4 += 1024) {
        int4 v = *(const int4*)&ei[E_DIM + e4 * 4];
        atomicAdd(&a[v.x], 1);
        atomicAdd(&a[v.y], 1);
        atomicAdd(&a[v.z], 1);
        atomicAdd(&a[v.w], 1);
    }
    __syncthreads();
    for (int i = tid; i < 2048; i += 1024) a[i] = (i < N_DIM) ? (a[i] + 1) : 0;
    __syncthreads();
    int* s = a; int* d = b;
    for (int off = 1; off < 2048; off <<= 1) {
        for (int i = tid; i < 2048; i += 1024)
            d[i] = s[i] + ((i >= off) ? s[i - off] : 0);
        __syncthreads();
        int* t = s; s = d; d = t;
    }
    for (int i = tid; i < 2048; i += 1024)
        if (i <= N_DIM) offs[i] = (i == 0) ? 0 : s[i - 1];
    for (int n = tid; n < N_DIM; n += 1024) {
        int pre = (n == 0) ? 0 : s[n - 1];
        int dp1 = s[n] - pre;                  // deg + 1 (self-loop)
        float dn = rsqrtf((float)dp1);
        dinv[n] = dn;
        edat[pre] = make_int2(n, __float_as_int(dn * dn));
        cursor[n] = 1;
    }
}

// ---------------- merged: CSR fill (blocks 0..124) + weight prep (blocks 125..188) ----------------
__global__ __launch_bounds__(256) void k_fillw(
    const int* __restrict__ ei, const int* __restrict__ offs,
    const float* __restrict__ dinv, int* __restrict__ cursor,
    int2* __restrict__ edat,
    const float* __restrict__ c1w, const float* __restrict__ c1b,
    const float* __restrict__ gw, const float* __restrict__ gb,
    const float* __restrict__ c2b, const float* __restrict__ c2w,
    ushort* __restrict__ W5f, ushort* __restrict__ Wc,
    float* __restrict__ bz, float* __restrict__ beta) {
    int tid = threadIdx.x;
    if (blockIdx.x < 125) {
        int e = blockIdx.x * 256 + tid;
        if (e < E_DIM) {
            int s = ei[e];
            int d = ei[E_DIM + e];
            int p = atomicAdd(&cursor[d], 1);
            edat[offs[d] + p] = make_int2(s, __float_as_int(dinv[s] * dinv[d]));
        }
        return;
    }
    __shared__ float Gl[3][64];
    __shared__ float b1l[64], gbl[64];
    int i = blockIdx.x - 125;
    if (tid < 192) {
        int j = tid >> 6, c = tid & 63;
        float s = 0.f;
        for (int o = 0; o < 64; ++o)
            s += c1w[o * 192 + i * 3 + j] * gw[o * 64 + c];
        Gl[j][c] = s;
    } else {
        int c = tid - 192;
        float s = 0.f;
        if (i == 0)
            for (int o = 0; o < 64; ++o) s += c1b[o] * gw[o * 64 + c];
        b1l[c] = s;
        gbl[c] = gb[c];
    }
    __syncthreads();
    if (tid < 64) {
        int n = tid;
        float d00 = 0.f, d01 = 0.f, d02 = 0.f;
        float d10 = 0.f, d11 = 0.f, d12 = 0.f;
        float d20 = 0.f, d21 = 0.f, d22 = 0.f;
        for (int c = 0; c < 64; ++c) {
            float a0 = Gl[0][c], a1 = Gl[1][c], a2 = Gl[2][c];
            float b0 = c2w[n * 192 + c * 3 + 0];
            float b1 = c2w[n * 192 + c * 3 + 1];
            float b2 = c2w[n * 192 + c * 3 + 2];
            d00 += a0 * b0; d01 += a0 * b1; d02 += a0 * b2;
            d10 += a1 * b0; d11 += a1 * b1; d12 += a1 * b2;
            d20 += a2 * b0; d21 += a2 * b1; d22 += a2 * b2;
        }
        float wm[5];
        wm[0] = d00;
        wm[1] = d01 + d10;
        wm[2] = d02 + d11 + d20;
        wm[3] = d12 + d21;
        wm[4] = d22;
        for (int m = 0; m < 5; ++m) {
            int kk = m * 64 + i;
            int flat = (((kk >> 5) * 4 + (n >> 4)) * 64 + ((kk >> 3) & 3) * 16 + (n & 15)) * 8 + (kk & 7);
            W5f[flat] = f2b(wm[m]);
        }
        int fc = (((i >> 5) * 4 + (n >> 4)) * 64 + ((i >> 3) & 3) * 16 + (n & 15)) * 8 + (i & 7);
        Wc[fc] = f2b(-d20);
        Wc[4096 + fc] = f2b(-d02);
        if (i == 0) {
            float s1[3] = {0.f, 0.f, 0.f}, s2[3] = {0.f, 0.f, 0.f};
            for (int k = 0; k < 3; ++k)
                for (int c = 0; c < 64; ++c) {
                    float w2 = c2w[n * 192 + c * 3 + k];
                    s1[k] += b1l[c] * w2;
                    s2[k] += gbl[c] * w2;
                }
            bz[n]        = s1[0] + s1[1] + s1[2];
            bz[64 + n]   = s1[1] + s1[2];
            bz[128 + n]  = s1[0] + s1[1];
            float cb = c2b[n];
            beta[n]       = s2[0] + s2[1] + s2[2] + cb;
            beta[64 + n]  = s2[1] + s2[2] + cb;
            beta[128 + n] = s2[0] + s2[1] + cb;
        }
    }
}

// ---------------- fused conv (K=320) with rolling t-window ----------------
// Block remap: XCD = tc>>1 so z writes for t-band g land in XCD g's L2 --
// the SAME L2 k_gather's band-g blocks will read from (producer/consumer align).
__global__ __launch_bounds__(256) void k_conv5(
    const float* __restrict__ x, const ushort* __restrict__ W5f,
    const ushort* __restrict__ Wcg, const float* __restrict__ bz,
    ushort* __restrict__ z) {
    __shared__ __align__(16) ushort Wl[20480];      // 40 KB
    __shared__ __align__(16) ushort Cl[4096];       // 8 KB corr
    __shared__ __align__(16) ushort Eb[4][1280];    // 10 KB epilogue (per wave)

    int tid = threadIdx.x, wv = tid >> 6, lane = tid & 63;
    int ml = lane & 15, q = lane >> 4;
    // XCD-aligned remap (bijective over 512 blocks):
    int L = blockIdx.x + 32 * blockIdx.y;
    int xcd = L & 7, slot = L >> 3;
    int nb = slot & 31;
    int tc = 2 * xcd + (slot >> 5);
    int n0 = nb * 64;
    int t0 = tc * TCHUNK;
    int n = n0 + wv * 16 + ml;
    bool nok = (n < N_DIM);
    const float* xrow = x + (size_t)n * 64 + q * 8;

    #pragma unroll
    for (int o = 0; o < 10; ++o) {
        int idx = tid + o * 256;
        *(s8v*)&Wl[idx * 8] = *(const s8v*)&W5f[idx * 8];
    }
    bool bnd0 = (t0 == 0), bnd1 = (t0 + TCHUNK == T_DIM);
    if (bnd0 || bnd1) {
        const ushort* src = Wcg + (bnd1 ? 4096 : 0);
        #pragma unroll
        for (int o = 0; o < 2; ++o) {
            int idx = tid + o * 256;
            *(s8v*)&Cl[idx * 8] = *(const s8v*)&src[idx * 8];
        }
    }

    const s8v ZV = {0, 0, 0, 0, 0, 0, 0, 0};
    s8v a[16];
    #pragma unroll
    for (int i = 0; i < 16; ++i) a[i] = ZV;

    #pragma unroll
    for (int i = 0; i < 5; ++i) {
        int s = t0 - 2 + i;
        if (nok && s >= 0 && s < T_DIM) {
            const float* p = xrow + (size_t)s * N_DIM * 64;
            float4 v0 = *(const float4*)p;
            float4 v1 = *(const float4*)(p + 4);
            float4 v2 = *(const float4*)(p + 32);
            float4 v3 = *(const float4*)(p + 36);
            a[2 * i]     = pack8(v0, v1);
            a[2 * i + 1] = pack8(v2, v3);
        }
    }
    __syncthreads();

    #pragma unroll
    for (int p = 0; p < TCHUNK; ++p) {
        int t = t0 + p;
        float4 r0, r1, r2, r3;
        bool pf = false;
        if (p < TCHUNK - 1) {
            int s = t0 + 3 + p;
            if (nok && s < T_DIM) {
                pf = true;
                const float* pp = xrow + (size_t)s * N_DIM * 64;
                r0 = *(const float4*)pp;
                r1 = *(const float4*)(pp + 4);
                r2 = *(const float4*)(pp + 32);
                r3 = *(const float4*)(pp + 36);
            }
        }

        f4v acc[4];
        #pragma unroll
        for (int c = 0; c < 4; ++c) acc[c] = (f4v){0.f, 0.f, 0.f, 0.f};

        #pragma unroll
        for (int sg = 0; sg < 10; ++sg) {
            #pragma unroll
            for (int c = 0; c < 4; ++c) {
                s8v bf = *(const s8v*)&Wl[((sg * 4 + c) * 64 + lane) * 8];
                acc[c] = __builtin_amdgcn_mfma_f32_16x16x32_bf16(a[2 * p + sg], bf, acc[c], 0, 0, 0);
            }
        }
        if (bnd0 && p == 0) {
            #pragma unroll
            for (int s2 = 0; s2 < 2; ++s2)
                #pragma unroll
                for (int c = 0; c < 4; ++c) {
                    s8v bf = *(const s8v*)&Cl[((s2 * 4 + c) * 64 + lane) * 8];
                    acc[c] = __builtin_amdgcn_mfma_f32_16x16x32_bf16(a[4 + s2], bf, acc[c], 0, 0, 0);
                }
        }
        if (bnd1 && p == TCHUNK - 1) {
            #pragma unroll
            for (int s2 = 0; s2 < 2; ++s2)
                #pragma unroll
                for (int c = 0; c < 4; ++c) {
                    s8v bf = *(const s8v*)&Cl[((s2 * 4 + c) * 64 + lane) * 8];
                    acc[c] = __builtin_amdgcn_mfma_f32_16x16x32_bf16(a[10 + s2], bf, acc[c], 0, 0, 0);
                }
        }

        int cls = (bnd0 && p == 0) ? 1 : ((bnd1 && p == TCHUNK - 1) ? 2 : 0);
        ushort* eb = &Eb[wv][0];
        #pragma unroll
        for (int c = 0; c < 4; ++c) {
            int col = c * 16 + ml;
            float bb = bz[cls * 64 + col];
            #pragma unroll
            for (int rg = 0; rg < 4; ++rg)
                eb[(q * 4 + rg) * 80 + col] = f2b(acc[c][rg] + bb);
        }
        int rr = lane >> 2, cof = (lane & 3) * 16;
        int gn = n0 + wv * 16 + rr;
        if (gn < N_DIM) {
            ushort* dst = &z[((size_t)t * N_DIM + gn) * 64 + cof];
            *(s8v*)dst       = *(const s8v*)&eb[rr * 80 + cof];
            *(s8v*)(dst + 8) = *(const s8v*)&eb[rr * 80 + cof + 8];
        }
        if (p < TCHUNK - 1) {
            a[10 + 2 * p] = pf ? pack8(r0, r1) : ZV;
            a[11 + 2 * p] = pf ? pack8(r2, r3) : ZV;
        }
    }
}

// ---------------- GCN aggregation: t-reuse + LDS edges + batch-8 pipeline,
// ATOMIC-FREE stats to pstats[128][2000], b = tg*250+nb (same-XCD adjacency). ----
__global__ __launch_bounds__(512) void k_gather(
    const ushort* __restrict__ zb, const int* __restrict__ offs,
    const int2* __restrict__ edat, const float* __restrict__ beta,
    ushort* __restrict__ yb, float* __restrict__ pstats) {
    __shared__ float ssum[64], ssq[64];
    __shared__ int2 eLds[GEMAX];
    __shared__ int eoff[9];
    int tid = threadIdx.x;
    if (tid < 64) { ssum[tid] = 0.f; ssq[tid] = 0.f; }

    int tg = blockIdx.x;                       // 0..7  (XCD band)
    int nb = blockIdx.y;                       // 0..249
    int n0 = nb * 8;
    if (tid < 9) eoff[tid] = offs[n0 + tid];
    __syncthreads();
    int ebase = eoff[0];
    int ecnt = eoff[8] - ebase;
    bool inLds = (ecnt <= GEMAX);
    if (inLds)
        for (int i = tid; i < ecnt; i += 512) eLds[i] = edat[ebase + i];
    __syncthreads();

    int wv = tid >> 6, lane = tid & 63;
    int u = lane >> 3;                         // t-slot 0..7
    int c8 = (lane & 7) * 8;                   // channel base
    int t = tg * 8 + u;
    int cls = (t == 0) ? 1 : ((t == 63) ? 2 : 0);
    const float* bp = beta + cls * 64 + c8;
    float4 b0 = *(const float4*)bp;
    float4 b1 = *(const float4*)(bp + 4);
    float bb[8] = {b0.x, b0.y, b0.z, b0.w, b1.x, b1.y, b1.z, b1.w};
    const ushort* zl = zb + (size_t)t * (N_DIM * 64) + c8;

    int n = n0 + wv;
    int beg = eoff[wv] - ebase;
    int len = eoff[wv + 1] - ebase - beg;

    float acc[8] = {0.f,0.f,0.f,0.f,0.f,0.f,0.f,0.f};

    if (inLds) {
        for (int k = 0; k < len; k += 8) {
            int2 e[8];
            #pragma unroll
            for (int i = 0; i < 8; ++i) {
                int kk = k + i;
                e[i] = eLds[beg + (kk < len ? kk : 0)];   // clamp: slot 0 is safe
            }
            s8v v[8];
            #pragma unroll
            for (int i = 0; i < 8; ++i)
                v[i] = *(const s8v*)(zl + (size_t)e[i].x * 64);
            #pragma unroll
            for (int i = 0; i < 8; ++i) {
                float w = (k + i < len) ? __int_as_float(e[i].y) : 0.f;
                #pragma unroll
                for (int j = 0; j < 8; ++j) acc[j] += w * b2f((ushort)v[i][j]);
            }
        }
    } else {                                   // pathological fallback (never in practice)
        const int2* eg = edat + ebase;
        for (int k = 0; k < len; ++k) {
            int2 e = eg[beg + k];
            float w = __int_as_float(e.y);
            s8v v = *(const s8v*)(zl + (size_t)e.x * 64);
            #pragma unroll
            for (int i = 0; i < 8; ++i) acc[i] += w * b2f((ushort)v[i]);
        }
    }

    float sr[8], qr[8];
    s8v pk;
    #pragma unroll
    for (int i = 0; i < 8; ++i) {
        float y = acc[i] + bb[i];
        pk[i] = (short)f2b(y);
        sr[i] = y;
        qr[i] = y * y;
    }
    *(s8v*)&yb[((size_t)t * N_DIM + n) * 64 + c8] = pk;

    // stats: reduce over t-slot bits, LDS-combine, NON-ATOMIC per-block store
    #pragma unroll
    for (int dd = 8; dd <= 32; dd <<= 1)
        #pragma unroll
        for (int i = 0; i < 8; ++i) {
            sr[i] += __shfl_xor(sr[i], dd);
            qr[i] += __shfl_xor(qr[i], dd);
        }
    if (u == 0) {
        #pragma unroll
        for (int i = 0; i < 8; ++i) {
            atomicAdd(&ssum[c8 + i], sr[i]);
            atomicAdd(&ssq[c8 + i], qr[i]);
        }
    }
    __syncthreads();
    int b = tg * 250 + nb;                     // same-XCD blocks own adjacent b
    if (tid < 64) {
        pstats[(size_t)tid * 2000 + b]        = ssum[tid];
        pstats[(size_t)(64 + tid) * 2000 + b] = ssq[tid];
    }
}

// ---------------- reduce per-block partials -> bnstats[128] ----------------
__global__ __launch_bounds__(256) void k_red(const float* __restrict__ pstats,
                                             float* __restrict__ bnstats) {
    __shared__ float ws[4];
    int row = blockIdx.x;                      // 0..127
    const float* p = pstats + (size_t)row * 2000;
    int tid = threadIdx.x;
    float s = 0.f;
    for (int i = tid; i < 2000; i += 256) s += p[i];
    #pragma unroll
    for (int d = 1; d < 64; d <<= 1) s += __shfl_xor(s, d);
    if ((tid & 63) == 0) ws[tid >> 6] = s;
    __syncthreads();
    if (tid == 0) bnstats[row] = ws[0] + ws[1] + ws[2] + ws[3];
}

// ---------------- BN apply + ReLU: y (bf16) -> out (fp32), t-banded, 32B/iter ----
// Grid dim3(8, 256): block (tg, by) processes band t in [8tg, 8tg+8) only --
// y was written into XCD tg's L2 by k_gather's band tg -> local-L2 reads.
__global__ __launch_bounds__(256) void k_bn(const ushort* __restrict__ yb,
                                            const float* __restrict__ bnstats,
                                            const float* __restrict__ gamma,
                                            const float* __restrict__ beta,
                                            float* __restrict__ out) {
    __shared__ float sscale[64], sshift[64];
    int tid = threadIdx.x;
    if (tid < 64) {
        float m = bnstats[tid] * (1.0f / ROWS);
        float v = bnstats[64 + tid] * (1.0f / ROWS) - m * m;
        float sc = gamma[tid] * rsqrtf(v + BN_EPS);
        sscale[tid] = sc;
        sshift[tid] = beta[tid] - m * sc;
    }
    __syncthreads();
    const int band16 = 8 * N_DIM * 4;          // 16-elem chunks per t-band = 64000
    size_t base16 = (size_t)blockIdx.x * band16;
    for (int i16 = blockIdx.y * 256 + tid; i16 < band16; i16 += 256 * 256) {
        size_t g = (base16 + i16) * 16;
        s8v va = *(const s8v*)&yb[g];
        s8v vb = *(const s8v*)&yb[g + 8];
        int cb = (i16 & 3) * 16;
        f4v o0, o1, o2, o3;
        o0[0] = fmaxf(b2f((ushort)va[0]) * sscale[cb + 0] + sshift[cb + 0], 0.f);
        o0[1] = fmaxf(b2f((ushort)va[1]) * sscale[cb + 1] + sshift[cb + 1], 0.f);
        o0[2] = fmaxf(b2f((ushort)va[2]) * sscale[cb + 2] + sshift[cb + 2], 0.f);
        o0[3] = fmaxf(b2f((ushort)va[3]) * sscale[cb + 3] + sshift[cb + 3], 0.f);
        o1[0] = fmaxf(b2f((ushort)va[4]) * sscale[cb + 4] + sshift[cb + 4], 0.f);
        o1[1] = fmaxf(b2f((ushort)va[5]) * sscale[cb + 5] + sshift[cb + 5], 0.f);
        o1[2] = fmaxf(b2f((ushort)va[6]) * sscale[cb + 6] + sshift[cb + 6], 0.f);
        o1[3] = fmaxf(b2f((ushort)va[7]) * sscale[cb + 7] + sshift[cb + 7], 0.f);
        o2[0] = fmaxf(b2f((ushort)vb[0]) * sscale[cb + 8] + sshift[cb + 8], 0.f);
        o2[1] = fmaxf(b2f((ushort)vb[1]) * sscale[cb + 9] + sshift[cb + 9], 0.f);
        o2[2] = fmaxf(b2f((ushort)vb[2]) * sscale[cb + 10] + sshift[cb + 10], 0.f);
        o2[3] = fmaxf(b2f((ushort)vb[3]) * sscale[cb + 11] + sshift[cb + 11], 0.f);
        o3[0] = fmaxf(b2f((ushort)vb[4]) * sscale[cb + 12] + sshift[cb + 12], 0.f);
        o3[1] = fmaxf(b2f((ushort)vb[5]) * sscale[cb + 13] + sshift[cb + 13], 0.f);
        o3[2] = fmaxf(b2f((ushort)vb[6]) * sscale[cb + 14] + sshift[cb + 14], 0.f);
        o3[3] = fmaxf(b2f((ushort)vb[7]) * sscale[cb + 15] + sshift[cb + 15], 0.f);
        __builtin_nontemporal_store(o0, (f4v*)&out[g]);
        __builtin_nontemporal_store(o1, (f4v*)&out[g + 4]);
        __builtin_nontemporal_store(o2, (f4v*)&out[g + 8]);
        __builtin_nontemporal_store(o3, (f4v*)&out[g + 12]);
    }
}

extern "C" void kernel_launch(void* const* d_in, const int* in_sizes, int n_in,
                              void* d_out, int out_size, void* d_ws, size_t ws_size,
                              hipStream_t stream) {
    const float* x   = (const float*)d_in[0];
    const int*   ei  = (const int*)d_in[1];
    const float* c1w = (const float*)d_in[2];
    const float* c1b = (const float*)d_in[3];
    const float* gw  = (const float*)d_in[4];
    const float* gb  = (const float*)d_in[5];
    const float* c2w = (const float*)d_in[6];
    const float* c2b = (const float*)d_in[7];
    const float* bng = (const float*)d_in[8];
    const float* bnb = (const float*)d_in[9];
    float* out = (float*)d_out;

    // workspace layout
    ushort* yb     = (ushort*)d_ws;                       // ROWS*64 bf16 = 16.4 MB
    ushort* W5f    = yb + (size_t)ROWS * 64;              // 20480 shorts
    ushort* Wc     = W5f + 20480;                         // 2*4096 shorts
    float*  bz     = (float*)(Wc + 8192);                 // 192
    float*  beta   = bz + 192;                            // 192
    float*  dinv   = beta + 192;                          // 2000
    float*  bnstats= dinv + 2000;                         // 128
    int*    offs   = (int*)(bnstats + 128);               // 2001
    int*    cursor = offs + 2001;                         // 2000
    int2*   edat   = (int2*)((char*)(cursor + 2000) +
                     (((size_t)(cursor + 2000)) % 8 ? 4 : 0)); // E+N int2
    float*  pstats = (float*)(edat + (E_DIM + N_DIM));    // 128*2000 = 1 MB

    ushort* zb = (ushort*)d_out;   // bf16 z parked in d_out (dead before k_bn writes)

    k_degscan<<<1, 1024, 0, stream>>>(ei, offs, dinv, cursor, edat);
    k_fillw<<<189, 256, 0, stream>>>(ei, offs, dinv, cursor, edat,
                                     c1w, c1b, gw, gb, c2b, c2w, W5f, Wc, bz, beta);
    // stage 1: fused conv (XCD-aligned z writes) -> z bf16 (d_out)
    k_conv5<<<dim3(32, T_DIM / TCHUNK), 256, 0, stream>>>(x, W5f, Wc, bz, zb);
    // stage 2: GCN aggregation (batch-8, atomic-free stats) -> y bf16 (ws) + pstats
    k_gather<<<dim3(8, 250), 512, 0, stream>>>(zb, offs, edat, beta, yb, pstats);
    // stage 2b: reduce partial stats
    k_red<<<128, 256, 0, stream>>>(pstats, bnstats);
    // stage 3: BN apply + ReLU (t-banded, y local-L2, 32B/iter) -> fp32 out
    k_bn<<<dim3(8, 256), 256, 0, stream>>>(yb, bnstats, bng, bnb, out);
}

// Round 17
// 175.173 us; speedup vs baseline: 1.0463x; 1.0463x over previous
//
#include <hip/hip_runtime.h>

#define T_DIM 64
#define N_DIM 2000
#define C_DIM 64
#define E_DIM 32000
#define ROWS (T_DIM * N_DIM)   // 128000
#define BN_EPS 1e-5f
#define TCHUNK 4
#define GEMAX 1024             // LDS edge buffer (block of 8 n's; E[sum deg+1]~136)

typedef short s8v __attribute__((ext_vector_type(8)));
typedef float f4v __attribute__((ext_vector_type(4)));

__device__ __forceinline__ ushort f2b(float f) {
    unsigned u = __float_as_uint(f);
    unsigned r = u + 0x7FFF + ((u >> 16) & 1);
    return (ushort)(r >> 16);
}
__device__ __forceinline__ float b2f(ushort h) {
    return __uint_as_float(((unsigned)h) << 16);
}
__device__ __forceinline__ s8v pack8(float4 a, float4 b) {
    s8v r;
    r[0] = (short)f2b(a.x); r[1] = (short)f2b(a.y);
    r[2] = (short)f2b(a.z); r[3] = (short)f2b(a.w);
    r[4] = (short)f2b(b.x); r[5] = (short)f2b(b.y);
    r[6] = (short)f2b(b.z); r[7] = (short)f2b(b.w);
    return r;
}

// ---------------- prep: deg (LDS atomics) + scan + dinv + self-edge + cursor ----------------
__global__ void k_degscan(const int* __restrict__ ei, int* __restrict__ offs,
                          float* __restrict__ dinv, int* __restrict__ cursor,
                          int2* __restrict__ edat) {
    __shared__ int a[2048], b[2048];
    int tid = threadIdx.x;
    for (int i = tid; i < 2048; i += 1024) a[i] = 0;
    __syncthreads();
    for (int e = tid; e < E_DIM; e += 1024) atomicAdd(&a[ei[E_DIM + e]], 1);
    __syncthreads();
    for (int i = tid; i < 2048; i += 1024) a[i] = (i < N_DIM) ? (a[i] + 1) : 0;
    __syncthreads();
    int* s = a; int* d = b;
    for (int off = 1; off < 2048; off <<= 1) {
        for (int i = tid; i < 2048; i += 1024)
            d[i] = s[i] + ((i >= off) ? s[i - off] : 0);
        __syncthreads();
        int* t = s; s = d; d = t;
    }
    for (int i = tid; i < 2048; i += 1024)
        if (i <= N_DIM) offs[i] = (i == 0) ? 0 : s[i - 1];
    for (int n = tid; n < N_DIM; n += 1024) {
        int pre = (n == 0) ? 0 : s[n - 1];
        int dp1 = s[n] - pre;                  // deg + 1 (self-loop)
        float dn = rsqrtf((float)dp1);
        dinv[n] = dn;
        edat[pre] = make_int2(n, __float_as_int(dn * dn));
        cursor[n] = 1;
    }
}

// ---------------- merged: CSR fill (blocks 0..124) + weight prep (blocks 125..188) ----------------
__global__ __launch_bounds__(256) void k_fillw(
    const int* __restrict__ ei, const int* __restrict__ offs,
    const float* __restrict__ dinv, int* __restrict__ cursor,
    int2* __restrict__ edat,
    const float* __restrict__ c1w, const float* __restrict__ c1b,
    const float* __restrict__ gw, const float* __restrict__ gb,
    const float* __restrict__ c2b, const float* __restrict__ c2w,
    ushort* __restrict__ W5f, ushort* __restrict__ Wc,
    float* __restrict__ bz, float* __restrict__ beta) {
    int tid = threadIdx.x;
    if (blockIdx.x < 125) {
        int e = blockIdx.x * 256 + tid;
        if (e < E_DIM) {
            int s = ei[e];
            int d = ei[E_DIM + e];
            int p = atomicAdd(&cursor[d], 1);
            edat[offs[d] + p] = make_int2(s, __float_as_int(dinv[s] * dinv[d]));
        }
        return;
    }
    __shared__ float Gl[3][64];
    __shared__ float b1l[64], gbl[64];
    int i = blockIdx.x - 125;
    if (tid < 192) {
        int j = tid >> 6, c = tid & 63;
        float s = 0.f;
        for (int o = 0; o < 64; ++o)
            s += c1w[o * 192 + i * 3 + j] * gw[o * 64 + c];
        Gl[j][c] = s;
    } else {
        int c = tid - 192;
        float s = 0.f;
        if (i == 0)
            for (int o = 0; o < 64; ++o) s += c1b[o] * gw[o * 64 + c];
        b1l[c] = s;
        gbl[c] = gb[c];
    }
    __syncthreads();
    if (tid < 64) {
        int n = tid;
        float d00 = 0.f, d01 = 0.f, d02 = 0.f;
        float d10 = 0.f, d11 = 0.f, d12 = 0.f;
        float d20 = 0.f, d21 = 0.f, d22 = 0.f;
        for (int c = 0; c < 64; ++c) {
            float a0 = Gl[0][c], a1 = Gl[1][c], a2 = Gl[2][c];
            float b0 = c2w[n * 192 + c * 3 + 0];
            float b1 = c2w[n * 192 + c * 3 + 1];
            float b2 = c2w[n * 192 + c * 3 + 2];
            d00 += a0 * b0; d01 += a0 * b1; d02 += a0 * b2;
            d10 += a1 * b0; d11 += a1 * b1; d12 += a1 * b2;
            d20 += a2 * b0; d21 += a2 * b1; d22 += a2 * b2;
        }
        float wm[5];
        wm[0] = d00;
        wm[1] = d01 + d10;
        wm[2] = d02 + d11 + d20;
        wm[3] = d12 + d21;
        wm[4] = d22;
        for (int m = 0; m < 5; ++m) {
            int kk = m * 64 + i;
            int flat = (((kk >> 5) * 4 + (n >> 4)) * 64 + ((kk >> 3) & 3) * 16 + (n & 15)) * 8 + (kk & 7);
            W5f[flat] = f2b(wm[m]);
        }
        int fc = (((i >> 5) * 4 + (n >> 4)) * 64 + ((i >> 3) & 3) * 16 + (n & 15)) * 8 + (i & 7);
        Wc[fc] = f2b(-d20);
        Wc[4096 + fc] = f2b(-d02);
        if (i == 0) {
            float s1[3] = {0.f, 0.f, 0.f}, s2[3] = {0.f, 0.f, 0.f};
            for (int k = 0; k < 3; ++k)
                for (int c = 0; c < 64; ++c) {
                    float w2 = c2w[n * 192 + c * 3 + k];
                    s1[k] += b1l[c] * w2;
                    s2[k] += gbl[c] * w2;
                }
            bz[n]        = s1[0] + s1[1] + s1[2];
            bz[64 + n]   = s1[1] + s1[2];
            bz[128 + n]  = s1[0] + s1[1];
            float cb = c2b[n];
            beta[n]       = s2[0] + s2[1] + s2[2] + cb;
            beta[64 + n]  = s2[1] + s2[2] + cb;
            beta[128 + n] = s2[0] + s2[1] + cb;
        }
    }
}

// ---------------- fused conv (K=320) with rolling t-window ----------------
// Block remap: XCD = tc>>1 so z writes for t-band g land in XCD g's L2 --
// the SAME L2 k_gather's band-g blocks will read from (producer/consumer align).
__global__ __launch_bounds__(256) void k_conv5(
    const float* __restrict__ x, const ushort* __restrict__ W5f,
    const ushort* __restrict__ Wcg, const float* __restrict__ bz,
    ushort* __restrict__ z) {
    __shared__ __align__(16) ushort Wl[20480];      // 40 KB
    __shared__ __align__(16) ushort Cl[4096];       // 8 KB corr
    __shared__ __align__(16) ushort Eb[4][1280];    // 10 KB epilogue (per wave)

    int tid = threadIdx.x, wv = tid >> 6, lane = tid & 63;
    int ml = lane & 15, q = lane >> 4;
    // XCD-aligned remap (bijective over 512 blocks):
    int L = blockIdx.x + 32 * blockIdx.y;
    int xcd = L & 7, slot = L >> 3;
    int nb = slot & 31;
    int tc = 2 * xcd + (slot >> 5);
    int n0 = nb * 64;
    int t0 = tc * TCHUNK;
    int n = n0 + wv * 16 + ml;
    bool nok = (n < N_DIM);
    const float* xrow = x + (size_t)n * 64 + q * 8;

    #pragma unroll
    for (int o = 0; o < 10; ++o) {
        int idx = tid + o * 256;
        *(s8v*)&Wl[idx * 8] = *(const s8v*)&W5f[idx * 8];
    }
    bool bnd0 = (t0 == 0), bnd1 = (t0 + TCHUNK == T_DIM);
    if (bnd0 || bnd1) {
        const ushort* src = Wcg + (bnd1 ? 4096 : 0);
        #pragma unroll
        for (int o = 0; o < 2; ++o) {
            int idx = tid + o * 256;
            *(s8v*)&Cl[idx * 8] = *(const s8v*)&src[idx * 8];
        }
    }

    const s8v ZV = {0, 0, 0, 0, 0, 0, 0, 0};
    s8v a[16];
    #pragma unroll
    for (int i = 0; i < 16; ++i) a[i] = ZV;

    #pragma unroll
    for (int i = 0; i < 5; ++i) {
        int s = t0 - 2 + i;
        if (nok && s >= 0 && s < T_DIM) {
            const float* p = xrow + (size_t)s * N_DIM * 64;
            float4 v0 = *(const float4*)p;
            float4 v1 = *(const float4*)(p + 4);
            float4 v2 = *(const float4*)(p + 32);
            float4 v3 = *(const float4*)(p + 36);
            a[2 * i]     = pack8(v0, v1);
            a[2 * i + 1] = pack8(v2, v3);
        }
    }
    __syncthreads();

    #pragma unroll
    for (int p = 0; p < TCHUNK; ++p) {
        int t = t0 + p;
        float4 r0, r1, r2, r3;
        bool pf = false;
        if (p < TCHUNK - 1) {
            int s = t0 + 3 + p;
            if (nok && s < T_DIM) {
                pf = true;
                const float* pp = xrow + (size_t)s * N_DIM * 64;
                r0 = *(const float4*)pp;
                r1 = *(const float4*)(pp + 4);
                r2 = *(const float4*)(pp + 32);
                r3 = *(const float4*)(pp + 36);
            }
        }

        f4v acc[4];
        #pragma unroll
        for (int c = 0; c < 4; ++c) acc[c] = (f4v){0.f, 0.f, 0.f, 0.f};

        #pragma unroll
        for (int sg = 0; sg < 10; ++sg) {
            #pragma unroll
            for (int c = 0; c < 4; ++c) {
                s8v bf = *(const s8v*)&Wl[((sg * 4 + c) * 64 + lane) * 8];
                acc[c] = __builtin_amdgcn_mfma_f32_16x16x32_bf16(a[2 * p + sg], bf, acc[c], 0, 0, 0);
            }
        }
        if (bnd0 && p == 0) {
            #pragma unroll
            for (int s2 = 0; s2 < 2; ++s2)
                #pragma unroll
                for (int c = 0; c < 4; ++c) {
                    s8v bf = *(const s8v*)&Cl[((s2 * 4 + c) * 64 + lane) * 8];
                    acc[c] = __builtin_amdgcn_mfma_f32_16x16x32_bf16(a[4 + s2], bf, acc[c], 0, 0, 0);
                }
        }
        if (bnd1 && p == TCHUNK - 1) {
            #pragma unroll
            for (int s2 = 0; s2 < 2; ++s2)
                #pragma unroll
                for (int c = 0; c < 4; ++c) {
                    s8v bf = *(const s8v*)&Cl[((s2 * 4 + c) * 64 + lane) * 8];
                    acc[c] = __builtin_amdgcn_mfma_f32_16x16x32_bf16(a[10 + s2], bf, acc[c], 0, 0, 0);
                }
        }

        int cls = (bnd0 && p == 0) ? 1 : ((bnd1 && p == TCHUNK - 1) ? 2 : 0);
        ushort* eb = &Eb[wv][0];
        #pragma unroll
        for (int c = 0; c < 4; ++c) {
            int col = c * 16 + ml;
            float bb = bz[cls * 64 + col];
            #pragma unroll
            for (int rg = 0; rg < 4; ++rg)
                eb[(q * 4 + rg) * 80 + col] = f2b(acc[c][rg] + bb);
        }
        int rr = lane >> 2, cof = (lane & 3) * 16;
        int gn = n0 + wv * 16 + rr;
        if (gn < N_DIM) {
            ushort* dst = &z[((size_t)t * N_DIM + gn) * 64 + cof];
            *(s8v*)dst       = *(const s8v*)&eb[rr * 80 + cof];
            *(s8v*)(dst + 8) = *(const s8v*)&eb[rr * 80 + cof + 8];
        }
        if (p < TCHUNK - 1) {
            a[10 + 2 * p] = pf ? pack8(r0, r1) : ZV;
            a[11 + 2 * p] = pf ? pack8(r2, r3) : ZV;
        }
    }
}

// ---------------- GCN aggregation: t-reuse + LDS edges + batch-8 pipeline,
// ATOMIC-FREE stats to pstats[128][2000], b = tg*250+nb (same-XCD adjacency). ----
__global__ __launch_bounds__(512) void k_gather(
    const ushort* __restrict__ zb, const int* __restrict__ offs,
    const int2* __restrict__ edat, const float* __restrict__ beta,
    ushort* __restrict__ yb, float* __restrict__ pstats) {
    __shared__ float ssum[64], ssq[64];
    __shared__ int2 eLds[GEMAX];
    __shared__ int eoff[9];
    int tid = threadIdx.x;
    if (tid < 64) { ssum[tid] = 0.f; ssq[tid] = 0.f; }

    int tg = blockIdx.x;                       // 0..7  (XCD band)
    int nb = blockIdx.y;                       // 0..249
    int n0 = nb * 8;
    if (tid < 9) eoff[tid] = offs[n0 + tid];
    __syncthreads();
    int ebase = eoff[0];
    int ecnt = eoff[8] - ebase;
    bool inLds = (ecnt <= GEMAX);
    if (inLds)
        for (int i = tid; i < ecnt; i += 512) eLds[i] = edat[ebase + i];
    __syncthreads();

    int wv = tid >> 6, lane = tid & 63;
    int u = lane >> 3;                         // t-slot 0..7
    int c8 = (lane & 7) * 8;                   // channel base
    int t = tg * 8 + u;
    int cls = (t == 0) ? 1 : ((t == 63) ? 2 : 0);
    const float* bp = beta + cls * 64 + c8;
    float4 b0 = *(const float4*)bp;
    float4 b1 = *(const float4*)(bp + 4);
    float bb[8] = {b0.x, b0.y, b0.z, b0.w, b1.x, b1.y, b1.z, b1.w};
    const ushort* zl = zb + (size_t)t * (N_DIM * 64) + c8;

    int n = n0 + wv;
    int beg = eoff[wv] - ebase;
    int len = eoff[wv + 1] - ebase - beg;

    float acc[8] = {0.f,0.f,0.f,0.f,0.f,0.f,0.f,0.f};

    if (inLds) {
        for (int k = 0; k < len; k += 8) {
            int2 e[8];
            #pragma unroll
            for (int i = 0; i < 8; ++i) {
                int kk = k + i;
                e[i] = eLds[beg + (kk < len ? kk : 0)];   // clamp: slot 0 is safe
            }
            s8v v[8];
            #pragma unroll
            for (int i = 0; i < 8; ++i)
                v[i] = *(const s8v*)(zl + (size_t)e[i].x * 64);
            #pragma unroll
            for (int i = 0; i < 8; ++i) {
                float w = (k + i < len) ? __int_as_float(e[i].y) : 0.f;
                #pragma unroll
                for (int j = 0; j < 8; ++j) acc[j] += w * b2f((ushort)v[i][j]);
            }
        }
    } else {                                   // pathological fallback (never in practice)
        const int2* eg = edat + ebase;
        for (int k = 0; k < len; ++k) {
            int2 e = eg[beg + k];
            float w = __int_as_float(e.y);
            s8v v = *(const s8v*)(zl + (size_t)e.x * 64);
            #pragma unroll
            for (int i = 0; i < 8; ++i) acc[i] += w * b2f((ushort)v[i]);
        }
    }

    float sr[8], qr[8];
    s8v pk;
    #pragma unroll
    for (int i = 0; i < 8; ++i) {
        float y = acc[i] + bb[i];
        pk[i] = (short)f2b(y);
        sr[i] = y;
        qr[i] = y * y;
    }
    *(s8v*)&yb[((size_t)t * N_DIM + n) * 64 + c8] = pk;

    // stats: reduce over t-slot bits, LDS-combine, NON-ATOMIC per-block store
    #pragma unroll
    for (int dd = 8; dd <= 32; dd <<= 1)
        #pragma unroll
        for (int i = 0; i < 8; ++i) {
            sr[i] += __shfl_xor(sr[i], dd);
            qr[i] += __shfl_xor(qr[i], dd);
        }
    if (u == 0) {
        #pragma unroll
        for (int i = 0; i < 8; ++i) {
            atomicAdd(&ssum[c8 + i], sr[i]);
            atomicAdd(&ssq[c8 + i], qr[i]);
        }
    }
    __syncthreads();
    int b = tg * 250 + nb;                     // same-XCD blocks own adjacent b
    if (tid < 64) {
        pstats[(size_t)tid * 2000 + b]        = ssum[tid];
        pstats[(size_t)(64 + tid) * 2000 + b] = ssq[tid];
    }
}

// ---------------- reduce per-block partials -> bnstats[128] ----------------
__global__ __launch_bounds__(256) void k_red(const float* __restrict__ pstats,
                                             float* __restrict__ bnstats) {
    __shared__ float ws[4];
    int row = blockIdx.x;                      // 0..127
    const float* p = pstats + (size_t)row * 2000;
    int tid = threadIdx.x;
    float s = 0.f;
    for (int i = tid; i < 2000; i += 256) s += p[i];
    #pragma unroll
    for (int d = 1; d < 64; d <<= 1) s += __shfl_xor(s, d);
    if ((tid & 63) == 0) ws[tid >> 6] = s;
    __syncthreads();
    if (tid == 0) bnstats[row] = ws[0] + ws[1] + ws[2] + ws[3];
}

// ---------------- BN apply + ReLU: y (bf16) -> out (fp32), t-banded ----------------
// Grid dim3(8, 256): block (tg, by) processes band t in [8tg, 8tg+8) only --
// y was written into XCD tg's L2 by k_gather's band tg -> local-L2 reads.
__global__ __launch_bounds__(256) void k_bn(const ushort* __restrict__ yb,
                                            const float* __restrict__ bnstats,
                                            const float* __restrict__ gamma,
                                            const float* __restrict__ beta,
                                            float* __restrict__ out) {
    __shared__ float sscale[64], sshift[64];
    int tid = threadIdx.x;
    if (tid < 64) {
        float m = bnstats[tid] * (1.0f / ROWS);
        float v = bnstats[64 + tid] * (1.0f / ROWS) - m * m;
        float sc = gamma[tid] * rsqrtf(v + BN_EPS);
        sscale[tid] = sc;
        sshift[tid] = beta[tid] - m * sc;
    }
    __syncthreads();
    const int band8 = 8 * N_DIM * 8;           // 8-elem chunks per t-band = 128000
    size_t base8 = (size_t)blockIdx.x * band8; // band start (chunk units)
    for (int i8 = blockIdx.y * 256 + tid; i8 < band8; i8 += 256 * 256) {
        size_t g8 = base8 + i8;
        s8v v = *(const s8v*)&yb[g8 * 8];
        int c8 = (i8 & 7) * 8;
        f4v o0, o1;
        o0[0] = fmaxf(b2f((ushort)v[0]) * sscale[c8 + 0] + sshift[c8 + 0], 0.f);
        o0[1] = fmaxf(b2f((ushort)v[1]) * sscale[c8 + 1] + sshift[c8 + 1], 0.f);
        o0[2] = fmaxf(b2f((ushort)v[2]) * sscale[c8 + 2] + sshift[c8 + 2], 0.f);
        o0[3] = fmaxf(b2f((ushort)v[3]) * sscale[c8 + 3] + sshift[c8 + 3], 0.f);
        o1[0] = fmaxf(b2f((ushort)v[4]) * sscale[c8 + 4] + sshift[c8 + 4], 0.f);
        o1[1] = fmaxf(b2f((ushort)v[5]) * sscale[c8 + 5] + sshift[c8 + 5], 0.f);
        o1[2] = fmaxf(b2f((ushort)v[6]) * sscale[c8 + 6] + sshift[c8 + 6], 0.f);
        o1[3] = fmaxf(b2f((ushort)v[7]) * sscale[c8 + 7] + sshift[c8 + 7], 0.f);
        __builtin_nontemporal_store(o0, (f4v*)&out[g8 * 8]);
        __builtin_nontemporal_store(o1, (f4v*)&out[g8 * 8 + 4]);
    }
}

extern "C" void kernel_launch(void* const* d_in, const int* in_sizes, int n_in,
                              void* d_out, int out_size, void* d_ws, size_t ws_size,
                              hipStream_t stream) {
    const float* x   = (const float*)d_in[0];
    const int*   ei  = (const int*)d_in[1];
    const float* c1w = (const float*)d_in[2];
    const float* c1b = (const float*)d_in[3];
    const float* gw  = (const float*)d_in[4];
    const float* gb  = (const float*)d_in[5];
    const float* c2w = (const float*)d_in[6];
    const float* c2b = (const float*)d_in[7];
    const float* bng = (const float*)d_in[8];
    const float* bnb = (const float*)d_in[9];
    float* out = (float*)d_out;

    // workspace layout
    ushort* yb     = (ushort*)d_ws;                       // ROWS*64 bf16 = 16.4 MB
    ushort* W5f    = yb + (size_t)ROWS * 64;              // 20480 shorts
    ushort* Wc     = W5f + 20480;                         // 2*4096 shorts
    float*  bz     = (float*)(Wc + 8192);                 // 192
    float*  beta   = bz + 192;                            // 192
    float*  dinv   = beta + 192;                          // 2000
    float*  bnstats= dinv + 2000;                         // 128
    int*    offs   = (int*)(bnstats + 128);               // 2001
    int*    cursor = offs + 2001;                         // 2000
    int2*   edat   = (int2*)((char*)(cursor + 2000) +
                     (((size_t)(cursor + 2000)) % 8 ? 4 : 0)); // E+N int2
    float*  pstats = (float*)(edat + (E_DIM + N_DIM));    // 128*2000 = 1 MB

    ushort* zb = (ushort*)d_out;   // bf16 z parked in d_out (dead before k_bn writes)

    k_degscan<<<1, 1024, 0, stream>>>(ei, offs, dinv, cursor, edat);
    k_fillw<<<189, 256, 0, stream>>>(ei, offs, dinv, cursor, edat,
                                     c1w, c1b, gw, gb, c2b, c2w, W5f, Wc, bz, beta);
    // stage 1: fused conv (XCD-aligned z writes) -> z bf16 (d_out)
    k_conv5<<<dim3(32, T_DIM / TCHUNK), 256, 0, stream>>>(x, W5f, Wc, bz, zb);
    // stage 2: GCN aggregation (batch-8, atomic-free stats) -> y bf16 (ws) + pstats
    k_gather<<<dim3(8, 250), 512, 0, stream>>>(zb, offs, edat, beta, yb, pstats);
    // stage 2b: reduce partial stats
    k_red<<<128, 256, 0, stream>>>(pstats, bnstats);
    // stage 3: BN apply + ReLU (t-banded, y local-L2) -> fp32 out
    k_bn<<<dim3(8, 256), 256, 0, stream>>>(yb, bnstats, bng, bnb, out);
}